// Round 8
// baseline (263.209 us; speedup 1.0000x reference)
//
#include <hip/hip_runtime.h>

// Causal single-head attention, B=4, S=4096, D=128, fp32 in/out.
// R15 = R12 exactly (proven: shuffle P-transpose, cvt_pk, bf16 Op, defer-max,
// 512-chunk table, V staged in LDS) + fa_merge FUSED into fa_fwd via split-K
// atomic fixup: per-(b,t) counter (zeroed by prep), release-fence + atomicAdd
// after Op/Ml write; last-arriving chunk block acquires and merges the tile.
// Removes one kernel launch + its gap. R13/R14 closed: V-staging is
// load-bearing (L2 latency in PV chain), launch_bounds(512,8) spills.

#define B_   4
#define S_   4096
#define D_   128
#define BN   64
#define NT_  64             // 64-key blobs per batch (prep granularity)
#define QT_  32             // q-tiles per batch (BM=128)
#define NCHB 128            // chunks per batch (table below)
#define BLOB_SHORTS 16384   // 32 KB per (b,kt): [K img 16KB][V^T img 16KB]
#define MASKVAL (-1.0e30f)
#define DEFER_THR 8.0f

// chunks per q-tile t (t=0..31), sum = 128; all chunk sizes <= 10 k-tiles
#define CHK_INIT {1,1,1,1, 2,2,2,2,2, 3,3,3,3,3, 4,4,4,4,4, 5,5,5,5, 6,6,6,6,6, 7,7,7, 8}
// BASE[t] = sum of CHK[tt] for tt > t (chunks enumerated t=31 downward)
#define BASE_INIT {127,126,125,124, 122,120,118,116,114, 111,108,105,102,99, \
                   95,91,87,83,79, 74,69,64,59, 53,47,41,35,29, 22,15,8, 0}

__constant__ short CHKd[32]  = CHK_INIT;
__constant__ short BASEd[32] = BASE_INIT;
constexpr short CHKh[32] = CHK_INIT;
constexpr short BASEh[32] = BASE_INIT;
constexpr int nchb_calc() { int s = 0; for (int t = 0; t < QT_; ++t) s += CHKh[t]; return s; }
static_assert(nchb_calc() == NCHB, "chunk count mismatch");
constexpr bool base_ok() {
    for (int t = 0; t < QT_; ++t) {
        int s = 0;
        for (int tt = t + 1; tt < QT_; ++tt) s += CHKh[tt];
        if (s != BASEh[t]) return false;
    }
    return true;
}
static_assert(base_ok(), "BASE table mismatch");

typedef __attribute__((ext_vector_type(8))) short bf16x8;
typedef __attribute__((ext_vector_type(4))) float f32x4;

__device__ __forceinline__ short f2bf(float x) {
    unsigned u = __builtin_bit_cast(unsigned, x);
    unsigned r = (u + 0x7fffu + ((u >> 16) & 1u)) >> 16;
    return (short)r;
}
__device__ __forceinline__ float ex2(float x) { return __builtin_amdgcn_exp2f(x); }
// RNE pack of two f32 -> one dword of 2 bf16 (lo=s0, hi=s1). gfx950 HW op.
__device__ __forceinline__ unsigned cvtpk(float lo, float hi) {
    unsigned r;
    asm("v_cvt_pk_bf16_f32 %0, %1, %2" : "=v"(r) : "v"(lo), "v"(hi));
    return r;
}
__device__ __forceinline__ void gl_lds16(const short* g, short* l) {
    __builtin_amdgcn_global_load_lds(
        (const __attribute__((address_space(1))) unsigned int*)g,
        (__attribute__((address_space(3))) unsigned int*)l, 16, 0, 0);
}

// ---------------- prep: 2048 blocks ---------------------------------------
__global__ __launch_bounds__(256) void prep(const float* __restrict__ Qg,
                                            const float* __restrict__ Kg,
                                            const float* __restrict__ Vg,
                                            short* __restrict__ Qbf,
                                            short* __restrict__ KV,
                                            int* __restrict__ Cnt)
{
    __shared__ short vt[64][40];
    const int id  = blockIdx.x;
    const int tid = threadIdx.x;
    const float SC = 0.12751740f;   // log2(e)/sqrt(128)

    if (id == 0 && tid < B_ * QT_) Cnt[tid] = 0;   // fixup counters (ws poisoned)

    if (id < 1024) {
        const int b = id & 3, tile = (id >> 2) & 63, q4 = id >> 8;
        const int n = q4 * 16 + (tid >> 4);
        const int G = tid & 15;
        const size_t rowoff = ((size_t)b * S_ + (size_t)tile * 64 + n) * D_ + G * 8;
        short* blob = KV + (size_t)(b * NT_ + tile) * BLOB_SHORTS;
        {
            float4 a = *reinterpret_cast<const float4*>(Qg + rowoff);
            float4 c = *reinterpret_cast<const float4*>(Qg + rowoff + 4);
            bf16x8 v;
            v[0] = f2bf(a.x * SC); v[1] = f2bf(a.y * SC); v[2] = f2bf(a.z * SC); v[3] = f2bf(a.w * SC);
            v[4] = f2bf(c.x * SC); v[5] = f2bf(c.y * SC); v[6] = f2bf(c.z * SC); v[7] = f2bf(c.w * SC);
            *reinterpret_cast<bf16x8*>(Qbf + rowoff) = v;
        }
        {
            float4 a = *reinterpret_cast<const float4*>(Kg + rowoff);
            float4 c = *reinterpret_cast<const float4*>(Kg + rowoff + 4);
            bf16x8 v;
            v[0] = f2bf(a.x); v[1] = f2bf(a.y); v[2] = f2bf(a.z); v[3] = f2bf(a.w);
            v[4] = f2bf(c.x); v[5] = f2bf(c.y); v[6] = f2bf(c.z); v[7] = f2bf(c.w);
            const int p = (G & 8) | ((G & 7) ^ (n & 7));
            *reinterpret_cast<bf16x8*>(blob + n * 128 + p * 8) = v;
        }
    } else {
        const int u = id - 1024;
        const int b = u & 3, tile = (u >> 2) & 63, dq = u >> 8;
        short* blob = KV + (size_t)(b * NT_ + tile) * BLOB_SHORTS;
        {
            const int n = tid >> 2, c8 = tid & 3;
            const size_t off = ((size_t)b * S_ + (size_t)tile * 64 + n) * D_ + dq * 32 + c8 * 8;
            float4 a = *reinterpret_cast<const float4*>(Vg + off);
            float4 c = *reinterpret_cast<const float4*>(Vg + off + 4);
            bf16x8 v;
            v[0] = f2bf(a.x); v[1] = f2bf(a.y); v[2] = f2bf(a.z); v[3] = f2bf(a.w);
            v[4] = f2bf(c.x); v[5] = f2bf(c.y); v[6] = f2bf(c.z); v[7] = f2bf(c.w);
            *reinterpret_cast<bf16x8*>(&vt[n][c8 * 8]) = v;
        }
        __syncthreads();
        {
            const int dl = tid >> 3, G = tid & 7;
            const int d  = dq * 32 + dl;
            bf16x8 g;
#pragma unroll
            for (int i = 0; i < 8; ++i) g[i] = vt[G * 8 + i][dl];
            const int p = G ^ (d & 7);
            *reinterpret_cast<bf16x8*>(blob + 8192 + d * 64 + p * 8) = g;
        }
    }
}

// ---------------- fa_fwd: 512 threads, BM=128, fused split-K fixup ---------
template<bool SPLIT>
__global__ __launch_bounds__(512, 4) void fa_fwd(const short* __restrict__ Qbf,
                                                 const short* __restrict__ KV,
                                                 float* __restrict__ Og,
                                                 unsigned* __restrict__ Op,
                                                 float* __restrict__ Ml,
                                                 int* __restrict__ Cnt)
{
    __shared__ short lkv[2][BLOB_SHORTS];   // 64 KB double buffer
    __shared__ int lastf;

    const int tid  = threadIdx.x;
    const int wv   = tid >> 6;      // 0..7: q-rows [wv*16, wv*16+16)
    const int lane = tid & 63;
    const int m    = lane & 15;
    const int quad = lane >> 4;
    const int m7   = m & 7;

    int batch, t, lo, hi, chunk_id, rt_chunks;
    {
        const int id = blockIdx.x;
        batch = id & 3;
        int u = id >> 2;
        if (SPLIT) {
            // chunk table walk, t = 31 downward (heavy q-tiles dispatch first)
            int tt = QT_ - 1, base = 0, rt;
            for (;;) { rt = CHKd[tt]; if (u < base + rt) break; base += rt; --tt; }
            t = tt;
            rt_chunks = rt;
            const int r  = u - base;
            const int nk = 2 * t + 2;
            lo = r * nk / rt;
            hi = (r + 1) * nk / rt;
            chunk_id = batch * NCHB + u;
        } else {
            t  = QT_ - 1 - u;
            lo = 0; hi = 2 * t + 2; chunk_id = 0; rt_chunks = 1;
        }
        if (lo >= hi) return;   // never in SPLIT (all chunks nonempty); safety
    }

    // Q fragment (pre-scaled bf16): q-row = t*128 + wv*16 + m
    bf16x8 qf[4];
    {
        const short* qp = Qbf + ((size_t)batch * S_ + (size_t)t * 128 + wv * 16 + m) * D_ + quad * 8;
#pragma unroll
        for (int c = 0; c < 4; ++c)
            qf[c] = *reinterpret_cast<const bf16x8*>(qp + c * 32);
    }

    f32x4 acc[8];
#pragma unroll
    for (int i = 0; i < 8; ++i) acc[i] = (f32x4){0.f, 0.f, 0.f, 0.f};
    float mrun = MASKVAL, lrun = 0.f;   // per-lane; lrun is a per-quad PARTIAL sum

    const size_t tilebase = (size_t)batch * NT_ * BLOB_SHORTS;
    const int qtop = t * 128 + wv * 16 + 15;   // max absolute q-row of this wave
#define STAGE(KT, BUF) do {                                                   \
        const short* g_ = KV + tilebase + (size_t)(KT) * BLOB_SHORTS + tid * 8;\
        short* l_ = (BUF) + tid * 8;                                          \
        _Pragma("unroll")                                                     \
        for (int c_ = 0; c_ < 4; ++c_)                                        \
            gl_lds16(g_ + c_ * 4096, l_ + c_ * 4096);                         \
    } while (0)

    STAGE(lo, lkv[0]);

    for (int kt = lo; kt < hi; ++kt) {
        const short* cur = lkv[(kt - lo) & 1];
        short* nxt = lkv[(kt - lo + 1) & 1];
        __syncthreads();   // vmcnt(0) drain: cur complete; prev reads of nxt done
        if (kt + 1 < hi) STAGE(kt + 1, nxt);   // in flight during compute

        // tile fully masked for this wave's q-rows -> contributes exactly 0
        if (kt * 64 > qtop) continue;

        const short* lk = cur;
        const short* lv = cur + 8192;

        // ---- S^T = K * Q^T : st[nt] rows k-local=quad*4+r, col q=m
        f32x4 st[4];
#pragma unroll
        for (int nt = 0; nt < 4; ++nt) st[nt] = (f32x4){0.f, 0.f, 0.f, 0.f};
        __builtin_amdgcn_s_setprio(1);
#pragma unroll
        for (int c = 0; c < 4; ++c) {
            const int p = ((c >> 1) * 8) | ((((c & 1) * 4) | quad) ^ m7);
#pragma unroll
            for (int nt = 0; nt < 4; ++nt) {
                bf16x8 kf = *reinterpret_cast<const bf16x8*>(lk + nt * 2048 + m * 128 + p * 8);
                st[nt] = __builtin_amdgcn_mfma_f32_16x16x32_bf16(kf, qf[c], st[nt], 0, 0, 0);
            }
        }
        __builtin_amdgcn_s_setprio(0);

        // ---- causal mask: only the last two k-tiles of this q-tile need it
        if (kt >= 2 * t) {
            const int kbase = (kt - 2 * t) * 64;   // 0 or 64
            const int qloc  = wv * 16 + m;
#pragma unroll
            for (int nt = 0; nt < 4; ++nt)
#pragma unroll
                for (int r = 0; r < 4; ++r)
                    if (kbase + nt * 16 + quad * 4 + r > qloc) st[nt][r] = MASKVAL;
        }

        // ---- online softmax, defer-max fast path (row = m; all-finite math)
        float t0 = fmaxf(fmaxf(st[0][0], st[0][1]), fmaxf(st[0][2], st[0][3]));
        float t1 = fmaxf(fmaxf(st[1][0], st[1][1]), fmaxf(st[1][2], st[1][3]));
        float t2 = fmaxf(fmaxf(st[2][0], st[2][1]), fmaxf(st[2][2], st[2][3]));
        float t3 = fmaxf(fmaxf(st[3][0], st[3][1]), fmaxf(st[3][2], st[3][3]));
        float mx = fmaxf(fmaxf(t0, t1), fmaxf(t2, t3));
        if (__any(mx - mrun > DEFER_THR)) {
            float mw = fmaxf(mx, __shfl_xor(mx, 16));
            mw = fmaxf(mw, __shfl_xor(mw, 32));
            const float mnew = fmaxf(mrun, mw);
            const float al   = ex2(mrun - mnew);   // finite-finite: never NaN
            mrun = mnew;
            lrun *= al;
#pragma unroll
            for (int r = 0; r < 4; ++r) {
                float alq = __shfl(al, quad * 4 + r);
#pragma unroll
                for (int ct = 0; ct < 8; ++ct) acc[ct][r] *= alq;
            }
        }
        float sum = 0.f;
#pragma unroll
        for (int nt = 0; nt < 4; ++nt)
#pragma unroll
            for (int r = 0; r < 4; ++r) {
                float pv = ex2(st[nt][r] - mrun);   // bounded by 2^THR
                st[nt][r] = pv;
                sum += pv;
            }
        lrun += sum;   // per-quad partial; reduced once after the loop

        // ---- PV with in-register P transpose (cvt_pk pack, shfl move)
        const int srcA = ((quad & 1) << 5) + m;
        const int srcB = srcA + 16;
        const bool loq = quad < 2;
#pragma unroll
        for (int ks = 0; ks < 2; ++ks) {
            unsigned pk0 = cvtpk(st[2 * ks][0],     st[2 * ks][1]);
            unsigned pk1 = cvtpk(st[2 * ks][2],     st[2 * ks][3]);
            unsigned pk2 = cvtpk(st[2 * ks + 1][0], st[2 * ks + 1][1]);
            unsigned pk3 = cvtpk(st[2 * ks + 1][2], st[2 * ks + 1][3]);
            unsigned w0a = __shfl((int)pk0, srcA);
            unsigned w0b = __shfl((int)pk2, srcA);
            unsigned w1a = __shfl((int)pk1, srcA);
            unsigned w1b = __shfl((int)pk3, srcA);
            unsigned w2a = __shfl((int)pk0, srcB);
            unsigned w2b = __shfl((int)pk2, srcB);
            unsigned w3a = __shfl((int)pk1, srcB);
            unsigned w3b = __shfl((int)pk3, srcB);
            int4 wi;
            wi.x = (int)(loq ? w0a : w0b);
            wi.y = (int)(loq ? w1a : w1b);
            wi.z = (int)(loq ? w2a : w2b);
            wi.w = (int)(loq ? w3a : w3b);
            bf16x8 pf = __builtin_bit_cast(bf16x8, wi);
            const int p = (ks * 4 + quad) ^ m7;
            __builtin_amdgcn_s_setprio(1);
#pragma unroll
            for (int ct = 0; ct < 8; ++ct) {
                bf16x8 vf = *reinterpret_cast<const bf16x8*>(lv + ct * 1024 + m * 64 + p * 8);
                acc[ct] = __builtin_amdgcn_mfma_f32_16x16x32_bf16(pf, vf, acc[ct], 0, 0, 0);
            }
            __builtin_amdgcn_s_setprio(0);
        }
    }
#undef STAGE

    // complete the deferred cross-quad row sum (row = m)
    lrun += __shfl_xor(lrun, 16);
    lrun += __shfl_xor(lrun, 32);

    const int row0 = wv * 16 + quad * 4;
    if (SPLIT) {
        // bf16 Op, lane-major permuted layout: row-dword G = m*4+j packs
        // (acc[2j], acc[2j+1]) = d-values {32j+m, 32j+16+m}. 32 KB / chunk.
        unsigned* ob = Op + (size_t)chunk_id * (128 * 64);
#pragma unroll
        for (int r = 0; r < 4; ++r) {
            uint4 w;
            w.x = cvtpk(acc[0][r], acc[1][r]);
            w.y = cvtpk(acc[2][r], acc[3][r]);
            w.z = cvtpk(acc[4][r], acc[5][r]);
            w.w = cvtpk(acc[6][r], acc[7][r]);
            *reinterpret_cast<uint4*>(ob + (row0 + r) * 64 + m * 4) = w;
        }
        if (lane < 16) {
            float* mlb = Ml + (size_t)chunk_id * (128 * 2) + (wv * 16 + lane) * 2;
            mlb[0] = mrun;
            mlb[1] = lrun;
        }

        // ---- split-K fixup: last-arriving chunk of (batch,t) merges the tile
        __threadfence();                        // release Op/Ml writes
        if (tid == 0) {
            int old = atomicAdd(&Cnt[batch * QT_ + t], 1);
            lastf = (old == rt_chunks - 1);
        }
        __syncthreads();
        if (!lastf) return;
        __threadfence();                        // acquire other chunks' writes

        const int cb = batch * NCHB + BASEd[t]; // first chunk id of this tile
        const int rt = rt_chunks;
        for (int i = tid; i < 4096; i += 512) { // 128 rows x 32 segments
            const int row = i >> 5;
            const int g   = i & 31;             // dwords 2g, 2g+1 of the row
            float mr_[8], lr_[8];
            float mg = MASKVAL;
#pragma unroll
            for (int r = 0; r < 8; ++r)
                if (r < rt) {
                    float2 ml2 = *reinterpret_cast<const float2*>(
                        Ml + (size_t)(cb + r) * (128 * 2) + row * 2);
                    mr_[r] = ml2.x;
                    lr_[r] = ml2.y;
                    mg = fmaxf(mg, mr_[r]);
                }
            float l = 0.f;
            float a0 = 0.f, a1 = 0.f, a2 = 0.f, a3 = 0.f;
#pragma unroll
            for (int r = 0; r < 8; ++r)
                if (r < rt) {
                    float w = ex2(mr_[r] - mg);  // fully-masked chunk -> w=0
                    l += lr_[r] * w;
                    uint2 pk = *reinterpret_cast<const uint2*>(
                        Op + (size_t)(cb + r) * (128 * 64) + row * 64 + g * 2);
                    a0 += w * __builtin_bit_cast(float, pk.x << 16);
                    a1 += w * __builtin_bit_cast(float, pk.x & 0xffff0000u);
                    a2 += w * __builtin_bit_cast(float, pk.y << 16);
                    a3 += w * __builtin_bit_cast(float, pk.y & 0xffff0000u);
                }
            const float inv = 1.0f / l;
            float* og = Og + ((size_t)batch * S_ + (size_t)t * 128 + row) * D_;
            const int d0 = 64 * (g & 1) + (g >> 1);   // m = g>>1, j0 = 2*(g&1)
            og[d0]      = a0 * inv;
            og[d0 + 16] = a1 * inv;
            og[d0 + 32] = a2 * inv;
            og[d0 + 48] = a3 * inv;
        }
    } else {
        const float inv = 1.0f / lrun;
        const size_t obase = ((size_t)batch * S_ + (size_t)t * 128 + row0) * D_;
#pragma unroll
        for (int r = 0; r < 4; ++r) {
            float invq = __shfl(inv, quad * 4 + r);
#pragma unroll
            for (int ct = 0; ct < 8; ++ct)
                Og[obase + (size_t)r * D_ + ct * 16 + m] = acc[ct][r] * invq;
        }
    }
}

extern "C" void kernel_launch(void* const* d_in, const int* in_sizes, int n_in,
                              void* d_out, int out_size, void* d_ws, size_t ws_size,
                              hipStream_t stream) {
    const float* q = (const float*)d_in[0];
    const float* k = (const float*)d_in[1];
    const float* v = (const float*)d_in[2];
    float* o = (float*)d_out;

    const size_t QBF_BYTES = (size_t)B_ * S_ * D_ * 2;              // 4 MB
    const size_t KV_BYTES  = (size_t)B_ * NT_ * BLOB_SHORTS * 2;    // 8 MB
    const size_t PREFIX    = QBF_BYTES + KV_BYTES;                  // 12 MB
    const int    NCH       = B_ * NCHB;                             // 512 chunks
    const size_t O_BYTES   = (size_t)NCH * 128 * 64 * 4;            // 16.8 MB (bf16)
    const size_t ML_BYTES  = (size_t)NCH * 128 * 2 * 4;
    const size_t CNT_BYTES = (size_t)(B_ * QT_) * 4;                // 512 B
    const size_t NEEDED    = PREFIX + O_BYTES + ML_BYTES + CNT_BYTES; // ~29.3 MB

    char* ws = (char*)d_ws;
    short* Qbf = (short*)ws;
    short* KV  = (short*)(ws + QBF_BYTES);
    unsigned* Op = (unsigned*)(ws + PREFIX);
    float* Ml = (float*)(ws + PREFIX + O_BYTES);
    int* Cnt = (int*)(ws + PREFIX + O_BYTES + ML_BYTES);

    prep<<<dim3(2048), 256, 0, stream>>>(q, k, v, Qbf, KV, Cnt);

    if (ws_size >= NEEDED) {
        fa_fwd<true><<<dim3(NCH), 512, 0, stream>>>(Qbf, KV, o, Op, Ml, Cnt);
    } else {
        fa_fwd<false><<<dim3(B_ * QT_), 512, 0, stream>>>(Qbf, KV, o, nullptr, nullptr, nullptr);
    }
}

// Round 9
// 112.307 us; speedup vs baseline: 2.3436x; 2.3436x over previous
//
#include <hip/hip_runtime.h>

// Causal single-head attention, B=4, S=4096, D=128, fp32 in/out.
// R16 = R10 VERBATIM (best measured: 114.6 us). Reverts R15's fence-based
// split-K fusion: device-scope __threadfence -> buffer_wbl2/buffer_inv per
// block trashed L2 (fa_fwd 203us, MfmaUtil 3.4%). Measured-closed levers:
// permlane transpose (R8/R11 fail), LDS-halving occupancy (R13 spill, R14
// V-latency exposed), chunk retable (R12 neutral), fence fusion (R15).
// Structure: prep (bf16+swizzled KV blobs) -> fa_fwd split chunks (online
// softmax, defer-max fast path, cvt_pk P-pack, shuffle transpose, bf16 Op)
// -> fa_merge.

#define B_   4
#define S_   4096
#define D_   128
#define BN   64
#define NT_  64             // 64-key blobs per batch (prep granularity)
#define QT_  32             // q-tiles per batch (BM=128)
#define NCHB 119            // chunks per batch: sum_t ceil((2t+2)/10)
#define BLOB_SHORTS 16384   // 32 KB per (b,kt): [K img 16KB][V^T img 16KB]
#define MASKVAL (-1.0e30f)
#define DEFER_THR 8.0f

typedef __attribute__((ext_vector_type(8))) short bf16x8;
typedef __attribute__((ext_vector_type(4))) float f32x4;

__device__ __host__ __forceinline__ constexpr int chunks_of(int t) { return (2 * t + 11) / 10; }
constexpr int nchb_calc() { int s = 0; for (int t = 0; t < QT_; ++t) s += chunks_of(t); return s; }
static_assert(nchb_calc() == NCHB, "chunk count mismatch");

__device__ __forceinline__ short f2bf(float x) {
    unsigned u = __builtin_bit_cast(unsigned, x);
    unsigned r = (u + 0x7fffu + ((u >> 16) & 1u)) >> 16;
    return (short)r;
}
__device__ __forceinline__ float ex2(float x) { return __builtin_amdgcn_exp2f(x); }
// RNE pack of two f32 -> one dword of 2 bf16 (lo=s0, hi=s1). gfx950 HW op.
__device__ __forceinline__ unsigned cvtpk(float lo, float hi) {
    unsigned r;
    asm("v_cvt_pk_bf16_f32 %0, %1, %2" : "=v"(r) : "v"(lo), "v"(hi));
    return r;
}
__device__ __forceinline__ void gl_lds16(const short* g, short* l) {
    __builtin_amdgcn_global_load_lds(
        (const __attribute__((address_space(1))) unsigned int*)g,
        (__attribute__((address_space(3))) unsigned int*)l, 16, 0, 0);
}

// ---------------- prep: 2048 blocks ---------------------------------------
__global__ __launch_bounds__(256) void prep(const float* __restrict__ Qg,
                                            const float* __restrict__ Kg,
                                            const float* __restrict__ Vg,
                                            short* __restrict__ Qbf,
                                            short* __restrict__ KV)
{
    __shared__ short vt[64][40];
    const int id  = blockIdx.x;
    const int tid = threadIdx.x;
    const float SC = 0.12751740f;   // log2(e)/sqrt(128)

    if (id < 1024) {
        const int b = id & 3, tile = (id >> 2) & 63, q4 = id >> 8;
        const int n = q4 * 16 + (tid >> 4);
        const int G = tid & 15;
        const size_t rowoff = ((size_t)b * S_ + (size_t)tile * 64 + n) * D_ + G * 8;
        short* blob = KV + (size_t)(b * NT_ + tile) * BLOB_SHORTS;
        {
            float4 a = *reinterpret_cast<const float4*>(Qg + rowoff);
            float4 c = *reinterpret_cast<const float4*>(Qg + rowoff + 4);
            bf16x8 v;
            v[0] = f2bf(a.x * SC); v[1] = f2bf(a.y * SC); v[2] = f2bf(a.z * SC); v[3] = f2bf(a.w * SC);
            v[4] = f2bf(c.x * SC); v[5] = f2bf(c.y * SC); v[6] = f2bf(c.z * SC); v[7] = f2bf(c.w * SC);
            *reinterpret_cast<bf16x8*>(Qbf + rowoff) = v;
        }
        {
            float4 a = *reinterpret_cast<const float4*>(Kg + rowoff);
            float4 c = *reinterpret_cast<const float4*>(Kg + rowoff + 4);
            bf16x8 v;
            v[0] = f2bf(a.x); v[1] = f2bf(a.y); v[2] = f2bf(a.z); v[3] = f2bf(a.w);
            v[4] = f2bf(c.x); v[5] = f2bf(c.y); v[6] = f2bf(c.z); v[7] = f2bf(c.w);
            const int p = (G & 8) | ((G & 7) ^ (n & 7));
            *reinterpret_cast<bf16x8*>(blob + n * 128 + p * 8) = v;
        }
    } else {
        const int u = id - 1024;
        const int b = u & 3, tile = (u >> 2) & 63, dq = u >> 8;
        short* blob = KV + (size_t)(b * NT_ + tile) * BLOB_SHORTS;
        {
            const int n = tid >> 2, c8 = tid & 3;
            const size_t off = ((size_t)b * S_ + (size_t)tile * 64 + n) * D_ + dq * 32 + c8 * 8;
            float4 a = *reinterpret_cast<const float4*>(Vg + off);
            float4 c = *reinterpret_cast<const float4*>(Vg + off + 4);
            bf16x8 v;
            v[0] = f2bf(a.x); v[1] = f2bf(a.y); v[2] = f2bf(a.z); v[3] = f2bf(a.w);
            v[4] = f2bf(c.x); v[5] = f2bf(c.y); v[6] = f2bf(c.z); v[7] = f2bf(c.w);
            *reinterpret_cast<bf16x8*>(&vt[n][c8 * 8]) = v;
        }
        __syncthreads();
        {
            const int dl = tid >> 3, G = tid & 7;
            const int d  = dq * 32 + dl;
            bf16x8 g;
#pragma unroll
            for (int i = 0; i < 8; ++i) g[i] = vt[G * 8 + i][dl];
            const int p = G ^ (d & 7);
            *reinterpret_cast<bf16x8*>(blob + 8192 + d * 64 + p * 8) = g;
        }
    }
}

// ---------------- fa_fwd: 512 threads, BM=128 ------------------------------
template<bool SPLIT>
__global__ __launch_bounds__(512, 4) void fa_fwd(const short* __restrict__ Qbf,
                                                 const short* __restrict__ KV,
                                                 float* __restrict__ Og,
                                                 unsigned* __restrict__ Op,
                                                 float* __restrict__ Ml)
{
    __shared__ short lkv[2][BLOB_SHORTS];   // 64 KB double buffer

    const int tid  = threadIdx.x;
    const int wv   = tid >> 6;      // 0..7: q-rows [wv*16, wv*16+16)
    const int lane = tid & 63;
    const int m    = lane & 15;
    const int quad = lane >> 4;
    const int m7   = m & 7;

    int batch, t, lo, hi, chunk_id;
    {
        const int id = blockIdx.x;
        batch = id & 3;
        int u = id >> 2;
        if (SPLIT) {
            // variable-R: R(t)=ceil((2t+2)/10); chunks enumerated t=31..0 (heavy first)
            int tt = QT_ - 1, base = 0, rt;
            for (;;) { rt = chunks_of(tt); if (u < base + rt) break; base += rt; --tt; }
            t = tt;
            const int r  = u - base;
            const int nk = 2 * t + 2;
            lo = r * nk / rt;
            hi = (r + 1) * nk / rt;
            chunk_id = batch * NCHB + u;
        } else {
            t  = QT_ - 1 - u;
            lo = 0; hi = 2 * t + 2; chunk_id = 0;
        }
        if (lo >= hi) return;   // never in SPLIT (all chunks nonempty); safety
    }

    // Q fragment (pre-scaled bf16): q-row = t*128 + wv*16 + m
    bf16x8 qf[4];
    {
        const short* qp = Qbf + ((size_t)batch * S_ + (size_t)t * 128 + wv * 16 + m) * D_ + quad * 8;
#pragma unroll
        for (int c = 0; c < 4; ++c)
            qf[c] = *reinterpret_cast<const bf16x8*>(qp + c * 32);
    }

    f32x4 acc[8];
#pragma unroll
    for (int i = 0; i < 8; ++i) acc[i] = (f32x4){0.f, 0.f, 0.f, 0.f};
    float mrun = MASKVAL, lrun = 0.f;   // per-lane; lrun is a per-quad PARTIAL sum

    const size_t tilebase = (size_t)batch * NT_ * BLOB_SHORTS;
    const int qtop = t * 128 + wv * 16 + 15;   // max absolute q-row of this wave
#define STAGE(KT, BUF) do {                                                   \
        const short* g_ = KV + tilebase + (size_t)(KT) * BLOB_SHORTS + tid * 8;\
        short* l_ = (BUF) + tid * 8;                                          \
        _Pragma("unroll")                                                     \
        for (int c_ = 0; c_ < 4; ++c_)                                        \
            gl_lds16(g_ + c_ * 4096, l_ + c_ * 4096);                         \
    } while (0)

    STAGE(lo, lkv[0]);

    for (int kt = lo; kt < hi; ++kt) {
        const short* cur = lkv[(kt - lo) & 1];
        short* nxt = lkv[(kt - lo + 1) & 1];
        __syncthreads();   // vmcnt(0) drain: cur complete; prev reads of nxt done
        if (kt + 1 < hi) STAGE(kt + 1, nxt);   // in flight during compute

        // tile fully masked for this wave's q-rows -> contributes exactly 0
        if (kt * 64 > qtop) continue;

        const short* lk = cur;
        const short* lv = cur + 8192;

        // ---- S^T = K * Q^T : st[nt] rows k-local=quad*4+r, col q=m
        f32x4 st[4];
#pragma unroll
        for (int nt = 0; nt < 4; ++nt) st[nt] = (f32x4){0.f, 0.f, 0.f, 0.f};
        __builtin_amdgcn_s_setprio(1);
#pragma unroll
        for (int c = 0; c < 4; ++c) {
            const int p = ((c >> 1) * 8) | ((((c & 1) * 4) | quad) ^ m7);
#pragma unroll
            for (int nt = 0; nt < 4; ++nt) {
                bf16x8 kf = *reinterpret_cast<const bf16x8*>(lk + nt * 2048 + m * 128 + p * 8);
                st[nt] = __builtin_amdgcn_mfma_f32_16x16x32_bf16(kf, qf[c], st[nt], 0, 0, 0);
            }
        }
        __builtin_amdgcn_s_setprio(0);

        // ---- causal mask: only the last two k-tiles of this q-tile need it
        if (kt >= 2 * t) {
            const int kbase = (kt - 2 * t) * 64;   // 0 or 64
            const int qloc  = wv * 16 + m;
#pragma unroll
            for (int nt = 0; nt < 4; ++nt)
#pragma unroll
                for (int r = 0; r < 4; ++r)
                    if (kbase + nt * 16 + quad * 4 + r > qloc) st[nt][r] = MASKVAL;
        }

        // ---- online softmax, defer-max fast path (row = m; all-finite math)
        // Per-lane max (depth-4 tree). If no lane exceeds mrun+THR, every row's
        // true max is <= its mrun+THR -> keep mrun, skip cross-quad reductions.
        float t0 = fmaxf(fmaxf(st[0][0], st[0][1]), fmaxf(st[0][2], st[0][3]));
        float t1 = fmaxf(fmaxf(st[1][0], st[1][1]), fmaxf(st[1][2], st[1][3]));
        float t2 = fmaxf(fmaxf(st[2][0], st[2][1]), fmaxf(st[2][2], st[2][3]));
        float t3 = fmaxf(fmaxf(st[3][0], st[3][1]), fmaxf(st[3][2], st[3][3]));
        float mx = fmaxf(fmaxf(t0, t1), fmaxf(t2, t3));
        if (__any(mx - mrun > DEFER_THR)) {
            float mw = fmaxf(mx, __shfl_xor(mx, 16));
            mw = fmaxf(mw, __shfl_xor(mw, 32));
            const float mnew = fmaxf(mrun, mw);
            const float al   = ex2(mrun - mnew);   // finite-finite: never NaN
            mrun = mnew;
            lrun *= al;
#pragma unroll
            for (int r = 0; r < 4; ++r) {
                float alq = __shfl(al, quad * 4 + r);
#pragma unroll
                for (int ct = 0; ct < 8; ++ct) acc[ct][r] *= alq;
            }
        }
        float sum = 0.f;
#pragma unroll
        for (int nt = 0; nt < 4; ++nt)
#pragma unroll
            for (int r = 0; r < 4; ++r) {
                float pv = ex2(st[nt][r] - mrun);   // bounded by 2^THR
                st[nt][r] = pv;
                sum += pv;
            }
        lrun += sum;   // per-quad partial; reduced once after the loop

        // ---- PV with in-register P transpose (cvt_pk pack, shfl move)
        const int srcA = ((quad & 1) << 5) + m;
        const int srcB = srcA + 16;
        const bool loq = quad < 2;
#pragma unroll
        for (int ks = 0; ks < 2; ++ks) {
            unsigned pk0 = cvtpk(st[2 * ks][0],     st[2 * ks][1]);
            unsigned pk1 = cvtpk(st[2 * ks][2],     st[2 * ks][3]);
            unsigned pk2 = cvtpk(st[2 * ks + 1][0], st[2 * ks + 1][1]);
            unsigned pk3 = cvtpk(st[2 * ks + 1][2], st[2 * ks + 1][3]);
            unsigned w0a = __shfl((int)pk0, srcA);
            unsigned w0b = __shfl((int)pk2, srcA);
            unsigned w1a = __shfl((int)pk1, srcA);
            unsigned w1b = __shfl((int)pk3, srcA);
            unsigned w2a = __shfl((int)pk0, srcB);
            unsigned w2b = __shfl((int)pk2, srcB);
            unsigned w3a = __shfl((int)pk1, srcB);
            unsigned w3b = __shfl((int)pk3, srcB);
            int4 wi;
            wi.x = (int)(loq ? w0a : w0b);
            wi.y = (int)(loq ? w1a : w1b);
            wi.z = (int)(loq ? w2a : w2b);
            wi.w = (int)(loq ? w3a : w3b);
            bf16x8 pf = __builtin_bit_cast(bf16x8, wi);
            const int p = (ks * 4 + quad) ^ m7;
            __builtin_amdgcn_s_setprio(1);
#pragma unroll
            for (int ct = 0; ct < 8; ++ct) {
                bf16x8 vf = *reinterpret_cast<const bf16x8*>(lv + ct * 1024 + m * 64 + p * 8);
                acc[ct] = __builtin_amdgcn_mfma_f32_16x16x32_bf16(pf, vf, acc[ct], 0, 0, 0);
            }
            __builtin_amdgcn_s_setprio(0);
        }
    }
#undef STAGE

    // complete the deferred cross-quad row sum (row = m)
    lrun += __shfl_xor(lrun, 16);
    lrun += __shfl_xor(lrun, 32);

    const int row0 = wv * 16 + quad * 4;
    if (SPLIT) {
        // bf16 Op, lane-major permuted layout: row-dword G = m*4+j packs
        // (acc[2j], acc[2j+1]) = d-values {32j+m, 32j+16+m}. 32 KB / chunk.
        unsigned* ob = Op + (size_t)chunk_id * (128 * 64);
#pragma unroll
        for (int r = 0; r < 4; ++r) {
            uint4 w;
            w.x = cvtpk(acc[0][r], acc[1][r]);
            w.y = cvtpk(acc[2][r], acc[3][r]);
            w.z = cvtpk(acc[4][r], acc[5][r]);
            w.w = cvtpk(acc[6][r], acc[7][r]);
            *reinterpret_cast<uint4*>(ob + (row0 + r) * 64 + m * 4) = w;
        }
        if (lane < 16) {
            float* mlb = Ml + (size_t)chunk_id * (128 * 2) + (wv * 16 + lane) * 2;
            mlb[0] = mrun;
            mlb[1] = lrun;
        }
    } else {
        const float inv = 1.0f / lrun;
        const size_t obase = ((size_t)batch * S_ + (size_t)t * 128 + row0) * D_;
#pragma unroll
        for (int r = 0; r < 4; ++r) {
            float invq = __shfl(inv, quad * 4 + r);
#pragma unroll
            for (int ct = 0; ct < 8; ++ct)
                Og[obase + (size_t)r * D_ + ct * 16 + m] = acc[ct][r] * invq;
        }
    }
}

// ---------------- merge: 2048 blocks, 8 rows each --------------------------
__global__ __launch_bounds__(256) void fa_merge(const unsigned* __restrict__ Op,
                                                const float* __restrict__ Ml,
                                                float* __restrict__ Og)
{
    const int x   = blockIdx.x;
    const int btq = x >> 4;                 // b*QT_ + t
    const int oct = x & 15;
    const int t   = btq & (QT_ - 1);
    const int b   = btq >> 5;
    const int rt  = chunks_of(t);
    int base = 0;
    for (int tt = QT_ - 1; tt > t; --tt) base += chunks_of(tt);
    const int cbase = b * NCHB + base;
    const int row = oct * 8 + (threadIdx.x >> 5);   // 0..127
    const int g   = threadIdx.x & 31;               // dwords 2g, 2g+1 of the row

    float mr_[7], lr_[7];                   // rt <= 7; static-indexed via unroll
    float mg = MASKVAL;
#pragma unroll
    for (int r = 0; r < 7; ++r)
        if (r < rt) {
            float2 ml2 = *reinterpret_cast<const float2*>(
                Ml + (size_t)(cbase + r) * (128 * 2) + row * 2);
            mr_[r] = ml2.x;
            lr_[r] = ml2.y;
            mg = fmaxf(mg, mr_[r]);
        }
    float l = 0.f;
    float a0 = 0.f, a1 = 0.f, a2 = 0.f, a3 = 0.f;
#pragma unroll
    for (int r = 0; r < 7; ++r)
        if (r < rt) {
            float w = ex2(mr_[r] - mg);     // fully-masked chunk underflows to 0
            l += lr_[r] * w;
            uint2 pk = *reinterpret_cast<const uint2*>(
                Op + (size_t)(cbase + r) * (128 * 64) + row * 64 + g * 2);
            a0 += w * __builtin_bit_cast(float, pk.x << 16);
            a1 += w * __builtin_bit_cast(float, pk.x & 0xffff0000u);
            a2 += w * __builtin_bit_cast(float, pk.y << 16);
            a3 += w * __builtin_bit_cast(float, pk.y & 0xffff0000u);
        }
    const float inv = 1.0f / l;
    float* og = Og + (size_t)btq * (128 * D_) + row * D_;
    const int d0 = 64 * (g & 1) + (g >> 1);   // m = g>>1, j0 = 2*(g&1)
    og[d0]      = a0 * inv;
    og[d0 + 16] = a1 * inv;
    og[d0 + 32] = a2 * inv;
    og[d0 + 48] = a3 * inv;
}

extern "C" void kernel_launch(void* const* d_in, const int* in_sizes, int n_in,
                              void* d_out, int out_size, void* d_ws, size_t ws_size,
                              hipStream_t stream) {
    const float* q = (const float*)d_in[0];
    const float* k = (const float*)d_in[1];
    const float* v = (const float*)d_in[2];
    float* o = (float*)d_out;

    const size_t QBF_BYTES = (size_t)B_ * S_ * D_ * 2;              // 4 MB
    const size_t KV_BYTES  = (size_t)B_ * NT_ * BLOB_SHORTS * 2;    // 8 MB
    const size_t PREFIX    = QBF_BYTES + KV_BYTES;                  // 12 MB
    const int    NCH       = B_ * NCHB;                             // 476 chunks
    const size_t O_BYTES   = (size_t)NCH * 128 * 64 * 4;            // 14.9 MB (bf16)
    const size_t ML_BYTES  = (size_t)NCH * 128 * 2 * 4;
    const size_t NEEDED    = PREFIX + O_BYTES + ML_BYTES;           // ~27.3 MB

    char* ws = (char*)d_ws;
    short* Qbf = (short*)ws;
    short* KV  = (short*)(ws + QBF_BYTES);

    prep<<<dim3(2048), 256, 0, stream>>>(q, k, v, Qbf, KV);

    if (ws_size >= NEEDED) {
        unsigned* Op = (unsigned*)(ws + PREFIX);
        float* Ml = (float*)(ws + PREFIX + O_BYTES);
        fa_fwd<true><<<dim3(NCH), 512, 0, stream>>>(Qbf, KV, nullptr, Op, Ml);
        fa_merge<<<dim3(B_ * QT_ * 16), 256, 0, stream>>>(Op, Ml, o);
    } else {
        fa_fwd<false><<<dim3(B_ * QT_), 512, 0, stream>>>(Qbf, KV, o, nullptr, nullptr);
    }
}

// Round 10
// 112.110 us; speedup vs baseline: 2.3478x; 1.0018x over previous
//
#include <hip/hip_runtime.h>

// Causal single-head attention, B=4, S=4096, D=128, fp32 in/out.
// R17 = R16 (= R10, best measured 112.3us) with the P-transpose moved from
// 16x ds_bpermute(__shfl) + 8x cndmask to a per-wave LDS scratch transpose:
// 4x ds_write_b64 + 1x ds_read_b128 per ks, XOR-swizzled (swz=(m&3)<<2) ->
// conflict-free at the HW minimum (writes 4/bank uniform, reads 8/bank
// uniform; verified by bank census). Within-wave only: lockstep + in-order
// LDS pipe => no barriers. Targets the constant 3.19M SQ_LDS_BANK_CONFLICT
// (R14 proved it's bpermute-driven, not V-staging). LDS 64+8=72KB -> still
// 2 blocks/CU. Permlane variants dropped permanently (R8/R11).

#define B_   4
#define S_   4096
#define D_   128
#define BN   64
#define NT_  64             // 64-key blobs per batch (prep granularity)
#define QT_  32             // q-tiles per batch (BM=128)
#define NCHB 119            // chunks per batch: sum_t ceil((2t+2)/10)
#define BLOB_SHORTS 16384   // 32 KB per (b,kt): [K img 16KB][V^T img 16KB]
#define MASKVAL (-1.0e30f)
#define DEFER_THR 8.0f

typedef __attribute__((ext_vector_type(8))) short bf16x8;
typedef __attribute__((ext_vector_type(4))) float f32x4;

__device__ __host__ __forceinline__ constexpr int chunks_of(int t) { return (2 * t + 11) / 10; }
constexpr int nchb_calc() { int s = 0; for (int t = 0; t < QT_; ++t) s += chunks_of(t); return s; }
static_assert(nchb_calc() == NCHB, "chunk count mismatch");

__device__ __forceinline__ short f2bf(float x) {
    unsigned u = __builtin_bit_cast(unsigned, x);
    unsigned r = (u + 0x7fffu + ((u >> 16) & 1u)) >> 16;
    return (short)r;
}
__device__ __forceinline__ float ex2(float x) { return __builtin_amdgcn_exp2f(x); }
// RNE pack of two f32 -> one dword of 2 bf16 (lo=s0, hi=s1). gfx950 HW op.
__device__ __forceinline__ unsigned cvtpk(float lo, float hi) {
    unsigned r;
    asm("v_cvt_pk_bf16_f32 %0, %1, %2" : "=v"(r) : "v"(lo), "v"(hi));
    return r;
}
__device__ __forceinline__ void gl_lds16(const short* g, short* l) {
    __builtin_amdgcn_global_load_lds(
        (const __attribute__((address_space(1))) unsigned int*)g,
        (__attribute__((address_space(3))) unsigned int*)l, 16, 0, 0);
}

// ---------------- prep: 2048 blocks ---------------------------------------
__global__ __launch_bounds__(256) void prep(const float* __restrict__ Qg,
                                            const float* __restrict__ Kg,
                                            const float* __restrict__ Vg,
                                            short* __restrict__ Qbf,
                                            short* __restrict__ KV)
{
    __shared__ short vt[64][40];
    const int id  = blockIdx.x;
    const int tid = threadIdx.x;
    const float SC = 0.12751740f;   // log2(e)/sqrt(128)

    if (id < 1024) {
        const int b = id & 3, tile = (id >> 2) & 63, q4 = id >> 8;
        const int n = q4 * 16 + (tid >> 4);
        const int G = tid & 15;
        const size_t rowoff = ((size_t)b * S_ + (size_t)tile * 64 + n) * D_ + G * 8;
        short* blob = KV + (size_t)(b * NT_ + tile) * BLOB_SHORTS;
        {
            float4 a = *reinterpret_cast<const float4*>(Qg + rowoff);
            float4 c = *reinterpret_cast<const float4*>(Qg + rowoff + 4);
            bf16x8 v;
            v[0] = f2bf(a.x * SC); v[1] = f2bf(a.y * SC); v[2] = f2bf(a.z * SC); v[3] = f2bf(a.w * SC);
            v[4] = f2bf(c.x * SC); v[5] = f2bf(c.y * SC); v[6] = f2bf(c.z * SC); v[7] = f2bf(c.w * SC);
            *reinterpret_cast<bf16x8*>(Qbf + rowoff) = v;
        }
        {
            float4 a = *reinterpret_cast<const float4*>(Kg + rowoff);
            float4 c = *reinterpret_cast<const float4*>(Kg + rowoff + 4);
            bf16x8 v;
            v[0] = f2bf(a.x); v[1] = f2bf(a.y); v[2] = f2bf(a.z); v[3] = f2bf(a.w);
            v[4] = f2bf(c.x); v[5] = f2bf(c.y); v[6] = f2bf(c.z); v[7] = f2bf(c.w);
            const int p = (G & 8) | ((G & 7) ^ (n & 7));
            *reinterpret_cast<bf16x8*>(blob + n * 128 + p * 8) = v;
        }
    } else {
        const int u = id - 1024;
        const int b = u & 3, tile = (u >> 2) & 63, dq = u >> 8;
        short* blob = KV + (size_t)(b * NT_ + tile) * BLOB_SHORTS;
        {
            const int n = tid >> 2, c8 = tid & 3;
            const size_t off = ((size_t)b * S_ + (size_t)tile * 64 + n) * D_ + dq * 32 + c8 * 8;
            float4 a = *reinterpret_cast<const float4*>(Vg + off);
            float4 c = *reinterpret_cast<const float4*>(Vg + off + 4);
            bf16x8 v;
            v[0] = f2bf(a.x); v[1] = f2bf(a.y); v[2] = f2bf(a.z); v[3] = f2bf(a.w);
            v[4] = f2bf(c.x); v[5] = f2bf(c.y); v[6] = f2bf(c.z); v[7] = f2bf(c.w);
            *reinterpret_cast<bf16x8*>(&vt[n][c8 * 8]) = v;
        }
        __syncthreads();
        {
            const int dl = tid >> 3, G = tid & 7;
            const int d  = dq * 32 + dl;
            bf16x8 g;
#pragma unroll
            for (int i = 0; i < 8; ++i) g[i] = vt[G * 8 + i][dl];
            const int p = G ^ (d & 7);
            *reinterpret_cast<bf16x8*>(blob + 8192 + d * 64 + p * 8) = g;
        }
    }
}

// ---------------- fa_fwd: 512 threads, BM=128 ------------------------------
template<bool SPLIT>
__global__ __launch_bounds__(512, 4) void fa_fwd(const short* __restrict__ Qbf,
                                                 const short* __restrict__ KV,
                                                 float* __restrict__ Og,
                                                 unsigned* __restrict__ Op,
                                                 float* __restrict__ Ml)
{
    __shared__ short lkv[2][BLOB_SHORTS];   // 64 KB double buffer
    __shared__ unsigned pbuf[8][256];       // 8 KB: per-wave P-transpose scratch

    const int tid  = threadIdx.x;
    const int wv   = tid >> 6;      // 0..7: q-rows [wv*16, wv*16+16)
    const int lane = tid & 63;
    const int m    = lane & 15;
    const int quad = lane >> 4;
    const int m7   = m & 7;

    int batch, t, lo, hi, chunk_id;
    {
        const int id = blockIdx.x;
        batch = id & 3;
        int u = id >> 2;
        if (SPLIT) {
            // variable-R: R(t)=ceil((2t+2)/10); chunks enumerated t=31..0 (heavy first)
            int tt = QT_ - 1, base = 0, rt;
            for (;;) { rt = chunks_of(tt); if (u < base + rt) break; base += rt; --tt; }
            t = tt;
            const int r  = u - base;
            const int nk = 2 * t + 2;
            lo = r * nk / rt;
            hi = (r + 1) * nk / rt;
            chunk_id = batch * NCHB + u;
        } else {
            t  = QT_ - 1 - u;
            lo = 0; hi = 2 * t + 2; chunk_id = 0;
        }
        if (lo >= hi) return;   // never in SPLIT (all chunks nonempty); safety
    }

    // Q fragment (pre-scaled bf16): q-row = t*128 + wv*16 + m
    bf16x8 qf[4];
    {
        const short* qp = Qbf + ((size_t)batch * S_ + (size_t)t * 128 + wv * 16 + m) * D_ + quad * 8;
#pragma unroll
        for (int c = 0; c < 4; ++c)
            qf[c] = *reinterpret_cast<const bf16x8*>(qp + c * 32);
    }

    f32x4 acc[8];
#pragma unroll
    for (int i = 0; i < 8; ++i) acc[i] = (f32x4){0.f, 0.f, 0.f, 0.f};
    float mrun = MASKVAL, lrun = 0.f;   // per-lane; lrun is a per-quad PARTIAL sum

    const size_t tilebase = (size_t)batch * NT_ * BLOB_SHORTS;
    const int qtop = t * 128 + wv * 16 + 15;   // max absolute q-row of this wave
#define STAGE(KT, BUF) do {                                                   \
        const short* g_ = KV + tilebase + (size_t)(KT) * BLOB_SHORTS + tid * 8;\
        short* l_ = (BUF) + tid * 8;                                          \
        _Pragma("unroll")                                                     \
        for (int c_ = 0; c_ < 4; ++c_)                                        \
            gl_lds16(g_ + c_ * 4096, l_ + c_ * 4096);                         \
    } while (0)

    STAGE(lo, lkv[0]);

    for (int kt = lo; kt < hi; ++kt) {
        const short* cur = lkv[(kt - lo) & 1];
        short* nxt = lkv[(kt - lo + 1) & 1];
        __syncthreads();   // vmcnt(0) drain: cur complete; prev reads of nxt done
        if (kt + 1 < hi) STAGE(kt + 1, nxt);   // in flight during compute

        // tile fully masked for this wave's q-rows -> contributes exactly 0
        if (kt * 64 > qtop) continue;

        const short* lk = cur;
        const short* lv = cur + 8192;

        // ---- S^T = K * Q^T : st[nt] rows k-local=quad*4+r, col q=m
        f32x4 st[4];
#pragma unroll
        for (int nt = 0; nt < 4; ++nt) st[nt] = (f32x4){0.f, 0.f, 0.f, 0.f};
        __builtin_amdgcn_s_setprio(1);
#pragma unroll
        for (int c = 0; c < 4; ++c) {
            const int p = ((c >> 1) * 8) | ((((c & 1) * 4) | quad) ^ m7);
#pragma unroll
            for (int nt = 0; nt < 4; ++nt) {
                bf16x8 kf = *reinterpret_cast<const bf16x8*>(lk + nt * 2048 + m * 128 + p * 8);
                st[nt] = __builtin_amdgcn_mfma_f32_16x16x32_bf16(kf, qf[c], st[nt], 0, 0, 0);
            }
        }
        __builtin_amdgcn_s_setprio(0);

        // ---- causal mask: only the last two k-tiles of this q-tile need it
        if (kt >= 2 * t) {
            const int kbase = (kt - 2 * t) * 64;   // 0 or 64
            const int qloc  = wv * 16 + m;
#pragma unroll
            for (int nt = 0; nt < 4; ++nt)
#pragma unroll
                for (int r = 0; r < 4; ++r)
                    if (kbase + nt * 16 + quad * 4 + r > qloc) st[nt][r] = MASKVAL;
        }

        // ---- online softmax, defer-max fast path (row = m; all-finite math)
        // Per-lane max (depth-4 tree). If no lane exceeds mrun+THR, every row's
        // true max is <= its mrun+THR -> keep mrun, skip cross-quad reductions.
        float t0 = fmaxf(fmaxf(st[0][0], st[0][1]), fmaxf(st[0][2], st[0][3]));
        float t1 = fmaxf(fmaxf(st[1][0], st[1][1]), fmaxf(st[1][2], st[1][3]));
        float t2 = fmaxf(fmaxf(st[2][0], st[2][1]), fmaxf(st[2][2], st[2][3]));
        float t3 = fmaxf(fmaxf(st[3][0], st[3][1]), fmaxf(st[3][2], st[3][3]));
        float mx = fmaxf(fmaxf(t0, t1), fmaxf(t2, t3));
        if (__any(mx - mrun > DEFER_THR)) {
            float mw = fmaxf(mx, __shfl_xor(mx, 16));
            mw = fmaxf(mw, __shfl_xor(mw, 32));
            const float mnew = fmaxf(mrun, mw);
            const float al   = ex2(mrun - mnew);   // finite-finite: never NaN
            mrun = mnew;
            lrun *= al;
#pragma unroll
            for (int r = 0; r < 4; ++r) {
                float alq = __shfl(al, quad * 4 + r);
#pragma unroll
                for (int ct = 0; ct < 8; ++ct) acc[ct][r] *= alq;
            }
        }
        float sum = 0.f;
#pragma unroll
        for (int nt = 0; nt < 4; ++nt)
#pragma unroll
            for (int r = 0; r < 4; ++r) {
                float pv = ex2(st[nt][r] - mrun);   // bounded by 2^THR
                st[nt][r] = pv;
                sum += pv;
            }
        lrun += sum;   // per-quad partial; reduced once after the loop

        // ---- PV: P transpose via per-wave LDS scratch (bedrock ds ops).
        // Write: lane (m,quad) stores pk(nt,rp) = P[m][k=nt*16+quad*4+2rp+{0,1}]
        //   at dword m*16 + ((h*8+quad*2+rp) ^ swz), h = nt&1, swz = (m&3)<<2
        //   (XOR on bits 2-3 only -> b64 pairs stay contiguous; bank census:
        //    16 starts x 4 lanes = conflict-free minimum).
        // Read: lane (m,quad) loads A-frag P[m][ks*32+quad*8+{0..7}] as one
        //   b128 at dword m*16 + ((quad*4) ^ swz) (8 starts x 8 lanes, min).
        // Same-wave lockstep + in-order LDS pipe: no barrier needed; ks=1
        // writes reuse the 1KB region after ks=0's read has issued.
        {
            unsigned* pb = &pbuf[wv][0];
            const int swz = (m & 3) << 2;
#pragma unroll
            for (int ks = 0; ks < 2; ++ks) {
#pragma unroll
                for (int h = 0; h < 2; ++h) {
                    const int nt = 2 * ks + h;
                    uint2 w;
                    w.x = cvtpk(st[nt][0], st[nt][1]);
                    w.y = cvtpk(st[nt][2], st[nt][3]);
                    *reinterpret_cast<uint2*>(pb + m * 16 + ((h * 8 + quad * 2) ^ swz)) = w;
                }
                uint4 wi = *reinterpret_cast<const uint4*>(pb + m * 16 + ((quad * 4) ^ swz));
                bf16x8 pf = __builtin_bit_cast(bf16x8, wi);
                const int p = (ks * 4 + quad) ^ m7;
                __builtin_amdgcn_s_setprio(1);
#pragma unroll
                for (int ct = 0; ct < 8; ++ct) {
                    bf16x8 vf = *reinterpret_cast<const bf16x8*>(lv + ct * 1024 + m * 64 + p * 8);
                    acc[ct] = __builtin_amdgcn_mfma_f32_16x16x32_bf16(pf, vf, acc[ct], 0, 0, 0);
                }
                __builtin_amdgcn_s_setprio(0);
            }
        }
    }
#undef STAGE

    // complete the deferred cross-quad row sum (row = m)
    lrun += __shfl_xor(lrun, 16);
    lrun += __shfl_xor(lrun, 32);

    const int row0 = wv * 16 + quad * 4;
    if (SPLIT) {
        // bf16 Op, lane-major permuted layout: row-dword G = m*4+j packs
        // (acc[2j], acc[2j+1]) = d-values {32j+m, 32j+16+m}. 32 KB / chunk.
        unsigned* ob = Op + (size_t)chunk_id * (128 * 64);
#pragma unroll
        for (int r = 0; r < 4; ++r) {
            uint4 w;
            w.x = cvtpk(acc[0][r], acc[1][r]);
            w.y = cvtpk(acc[2][r], acc[3][r]);
            w.z = cvtpk(acc[4][r], acc[5][r]);
            w.w = cvtpk(acc[6][r], acc[7][r]);
            *reinterpret_cast<uint4*>(ob + (row0 + r) * 64 + m * 4) = w;
        }
        if (lane < 16) {
            float* mlb = Ml + (size_t)chunk_id * (128 * 2) + (wv * 16 + lane) * 2;
            mlb[0] = mrun;
            mlb[1] = lrun;
        }
    } else {
        const float inv = 1.0f / lrun;
        const size_t obase = ((size_t)batch * S_ + (size_t)t * 128 + row0) * D_;
#pragma unroll
        for (int r = 0; r < 4; ++r) {
            float invq = __shfl(inv, quad * 4 + r);
#pragma unroll
            for (int ct = 0; ct < 8; ++ct)
                Og[obase + (size_t)r * D_ + ct * 16 + m] = acc[ct][r] * invq;
        }
    }
}

// ---------------- merge: 2048 blocks, 8 rows each --------------------------
__global__ __launch_bounds__(256) void fa_merge(const unsigned* __restrict__ Op,
                                                const float* __restrict__ Ml,
                                                float* __restrict__ Og)
{
    const int x   = blockIdx.x;
    const int btq = x >> 4;                 // b*QT_ + t
    const int oct = x & 15;
    const int t   = btq & (QT_ - 1);
    const int b   = btq >> 5;
    const int rt  = chunks_of(t);
    int base = 0;
    for (int tt = QT_ - 1; tt > t; --tt) base += chunks_of(tt);
    const int cbase = b * NCHB + base;
    const int row = oct * 8 + (threadIdx.x >> 5);   // 0..127
    const int g   = threadIdx.x & 31;               // dwords 2g, 2g+1 of the row

    float mr_[7], lr_[7];                   // rt <= 7; static-indexed via unroll
    float mg = MASKVAL;
#pragma unroll
    for (int r = 0; r < 7; ++r)
        if (r < rt) {
            float2 ml2 = *reinterpret_cast<const float2*>(
                Ml + (size_t)(cbase + r) * (128 * 2) + row * 2);
            mr_[r] = ml2.x;
            lr_[r] = ml2.y;
            mg = fmaxf(mg, mr_[r]);
        }
    float l = 0.f;
    float a0 = 0.f, a1 = 0.f, a2 = 0.f, a3 = 0.f;
#pragma unroll
    for (int r = 0; r < 7; ++r)
        if (r < rt) {
            float w = ex2(mr_[r] - mg);     // fully-masked chunk underflows to 0
            l += lr_[r] * w;
            uint2 pk = *reinterpret_cast<const uint2*>(
                Op + (size_t)(cbase + r) * (128 * 64) + row * 64 + g * 2);
            a0 += w * __builtin_bit_cast(float, pk.x << 16);
            a1 += w * __builtin_bit_cast(float, pk.x & 0xffff0000u);
            a2 += w * __builtin_bit_cast(float, pk.y << 16);
            a3 += w * __builtin_bit_cast(float, pk.y & 0xffff0000u);
        }
    const float inv = 1.0f / l;
    float* og = Og + (size_t)btq * (128 * D_) + row * D_;
    const int d0 = 64 * (g & 1) + (g >> 1);   // m = g>>1, j0 = 2*(g&1)
    og[d0]      = a0 * inv;
    og[d0 + 16] = a1 * inv;
    og[d0 + 32] = a2 * inv;
    og[d0 + 48] = a3 * inv;
}

extern "C" void kernel_launch(void* const* d_in, const int* in_sizes, int n_in,
                              void* d_out, int out_size, void* d_ws, size_t ws_size,
                              hipStream_t stream) {
    const float* q = (const float*)d_in[0];
    const float* k = (const float*)d_in[1];
    const float* v = (const float*)d_in[2];
    float* o = (float*)d_out;

    const size_t QBF_BYTES = (size_t)B_ * S_ * D_ * 2;              // 4 MB
    const size_t KV_BYTES  = (size_t)B_ * NT_ * BLOB_SHORTS * 2;    // 8 MB
    const size_t PREFIX    = QBF_BYTES + KV_BYTES;                  // 12 MB
    const int    NCH       = B_ * NCHB;                             // 476 chunks
    const size_t O_BYTES   = (size_t)NCH * 128 * 64 * 4;            // 14.9 MB (bf16)
    const size_t ML_BYTES  = (size_t)NCH * 128 * 2 * 4;
    const size_t NEEDED    = PREFIX + O_BYTES + ML_BYTES;           // ~27.3 MB

    char* ws = (char*)d_ws;
    short* Qbf = (short*)ws;
    short* KV  = (short*)(ws + QBF_BYTES);

    prep<<<dim3(2048), 256, 0, stream>>>(q, k, v, Qbf, KV);

    if (ws_size >= NEEDED) {
        unsigned* Op = (unsigned*)(ws + PREFIX);
        float* Ml = (float*)(ws + PREFIX + O_BYTES);
        fa_fwd<true><<<dim3(NCH), 512, 0, stream>>>(Qbf, KV, nullptr, Op, Ml);
        fa_merge<<<dim3(B_ * QT_ * 16), 256, 0, stream>>>(Op, Ml, o);
    } else {
        fa_fwd<false><<<dim3(B_ * QT_), 512, 0, stream>>>(Qbf, KV, o, nullptr, nullptr);
    }
}